// Round 3
// baseline (312.315 us; speedup 1.0000x reference)
//
#include <hip/hip_runtime.h>

// UnigramLM forward-backward posterior, T=2048, L=8, V=32000.
// R10: structure = pure fill, then fused fwd||bwd scan + atomic scatter.
//   Kernel 1 (fill): 2048 blocks x 256 thr, ZERO LDS, no sync, no branches —
//     pure float4 zero-stream, one 128KB row per block (rocclr-style; rocclr
//     hits 6.6 TB/s at ~3 waves/CU, so cleanliness > occupancy).
//   Kernel 2 (scan_scatter): ONE block x 1024 thr. Canonical w[t][j] staged
//     ONCE in LDS (CPAD chunk layout: stride 260 words == 4 mod 32 banks ->
//     conflict-free for BOTH row reads (bwd, b128) and diagonal reads (fwd,
//     8x b32)). Warps 0-7 = forward scan, warps 8-15 = backward scan, run
//     concurrently through the 3-phase chunked scan. Then all 1024 threads
//     scatter 16K posterior values via atomicAdd (stream-ordered after fill,
//     so duplicates are handled for free and the fill needs no skip logic).

#define NEGV -1e9f
#define LOG2E 1.4426950408889634f
constexpr int T = 2048;
constexpr int L = 8;
constexpr int V = 32000;
constexpr int NCH = 64;   // chunks per scan
constexpr int K = 32;     // steps per chunk (NCH*K == T)
constexpr int CPAD = K * 8 + 4;    // 260 words per 32-row chunk (bank swizzle)
constexpr int R4 = V / 4;          // 8000 float4 per row

__device__ __forceinline__ float hexp2(float x) { return __builtin_amdgcn_exp2f(x); }
__device__ __forceinline__ float hlog2(float x) { return __builtin_amdgcn_logf(x); }

// canonical LDS address of w[t][j]
__device__ __forceinline__ int swa(int t, int j) {
    return ((t >> 5) * CPAD) + ((t & 31) << 3) + j;
}

__device__ __forceinline__ float lse8v(float t0, float t1, float t2, float t3,
                                       float t4, float t5, float t6, float t7) {
    float m = fmaxf(fmaxf(fmaxf(t0, t1), fmaxf(t2, t3)),
                    fmaxf(fmaxf(t4, t5), fmaxf(t6, t7)));
    float s = hexp2(t0 - m) + hexp2(t1 - m) + hexp2(t2 - m) + hexp2(t3 - m)
            + hexp2(t4 - m) + hexp2(t5 - m) + hexp2(t6 - m) + hexp2(t7 - m);
    return m + hlog2(s);
}

__global__ __launch_bounds__(256) void fill_kernel(float* __restrict__ out) {
    const int t = blockIdx.x;          // one row per block
    float4 z = make_float4(0.f, 0.f, 0.f, 0.f);
    float4* o4 = (float4*)(out + (size_t)t * V);
    for (int i = threadIdx.x; i < R4; i += 256) o4[i] = z;
}

__global__ __launch_bounds__(1024) void scan_scatter_kernel(
        const float* __restrict__ logp, const int* __restrict__ midx,
        float* __restrict__ out) {
    const int tid = threadIdx.x;
    const int half = tid >> 9;         // 0 = forward, 1 = backward
    const int tl = tid & 511;

    __shared__ __align__(16) float sW[NCH * CPAD];    // 66,560 B canonical w (log2)
    __shared__ __align__(16) float sPm[2][NCH * 64];  // 32,768 B chunk operators
    __shared__ float sVst[2][NCH * 8];                //  4,096 B boundary states
    __shared__ float sOut[2][NCH * 33];               // 16,896 B padded emit bufs
    // total 120,320 B (single block on one CU)

    // ---- stage canonical w[t][j] once (all 1024 threads, coalesced) ----
    for (int o = tid; o < T * L; o += 1024) {
        int m = midx[o];
        sW[swa(o >> 3, o & 7)] = (m >= 0) ? logp[m] * LOG2E : NEGV;
    }
    __syncthreads();

    // ---- phase 1: operator composition; per half: thread (c, col) ----
    {
        const int c = tl >> 3, col = tl & 7;
        float q[8];
#pragma unroll
        for (int i = 0; i < 8; ++i) q[i] = (i == col) ? 0.f : NEGV;
        for (int k = 0; k < K; ++k) {
            float v[8];
            if (half == 0) {           // fwd: wrev[r][j] = w[r-j][j] (diagonal)
                int r = c * K + k;
#pragma unroll
                for (int j = 0; j < 8; ++j) {
                    int t = r - j;
                    v[j] = (t >= 0) ? sW[swa(t, j)] : NEGV;
                }
            } else {                   // bwd: row w[T-1-s][j] (contiguous)
                int t = T - 1 - (c * K + k);
                float4 r0 = *(const float4*)&sW[swa(t, 0)];
                float4 r1 = *(const float4*)&sW[swa(t, 4)];
                v[0] = r0.x; v[1] = r0.y; v[2] = r0.z; v[3] = r0.w;
                v[4] = r1.x; v[5] = r1.y; v[6] = r1.z; v[7] = r1.w;
            }
            float top = lse8v(v[0] + q[0], v[1] + q[1], v[2] + q[2], v[3] + q[3],
                              v[4] + q[4], v[5] + q[5], v[6] + q[6], v[7] + q[7]);
#pragma unroll
            for (int i = 7; i > 0; --i) q[i] = q[i - 1];
            q[0] = top;
        }
#pragma unroll
        for (int i = 0; i < 8; ++i) sPm[half][c * 64 + i * 8 + col] = q[i];
    }
    __syncthreads();

    // ---- phase 2: sequential combine across chunks (lanes 0..7 per half) ----
    if (tl < 8) {
        const int r = tl;
        float v = (r == 0) ? 0.f : NEGV;
        float4 r0 = *(const float4*)&sPm[half][r * 8];
        float4 r1 = *(const float4*)&sPm[half][r * 8 + 4];
        for (int cc = 0; cc < NCH; ++cc) {
            sVst[half][cc * 8 + r] = v;
            float4 n0, n1;
            if (cc + 1 < NCH) {
                n0 = *(const float4*)&sPm[half][(cc + 1) * 64 + r * 8];
                n1 = *(const float4*)&sPm[half][(cc + 1) * 64 + r * 8 + 4];
            }
            float vb0 = __shfl(v, 0, 8), vb1 = __shfl(v, 1, 8);
            float vb2 = __shfl(v, 2, 8), vb3 = __shfl(v, 3, 8);
            float vb4 = __shfl(v, 4, 8), vb5 = __shfl(v, 5, 8);
            float vb6 = __shfl(v, 6, 8), vb7 = __shfl(v, 7, 8);
            v = lse8v(r0.x + vb0, r0.y + vb1, r0.z + vb2, r0.w + vb3,
                      r1.x + vb4, r1.y + vb5, r1.z + vb6, r1.w + vb7);
            r0 = n0; r1 = n1;
        }
    }
    __syncthreads();

    // ---- phase 3: re-run each chunk from boundary state into padded emit ----
    if (tl < NCH) {
        const int cc = tl;
        float ab[8];
#pragma unroll
        for (int i = 0; i < 8; ++i) ab[i] = sVst[half][cc * 8 + i];
        for (int k = 0; k < K; ++k) {
            float v[8];
            if (half == 0) {
                int r = cc * K + k;
#pragma unroll
                for (int j = 0; j < 8; ++j) {
                    int t = r - j;
                    v[j] = (t >= 0) ? sW[swa(t, j)] : NEGV;
                }
            } else {
                int t = T - 1 - (cc * K + k);
                float4 r0 = *(const float4*)&sW[swa(t, 0)];
                float4 r1 = *(const float4*)&sW[swa(t, 4)];
                v[0] = r0.x; v[1] = r0.y; v[2] = r0.z; v[3] = r0.w;
                v[4] = r1.x; v[5] = r1.y; v[6] = r1.z; v[7] = r1.w;
            }
            float val = lse8v(v[0] + ab[0], v[1] + ab[1], v[2] + ab[2], v[3] + ab[3],
                              v[4] + ab[4], v[5] + ab[5], v[6] + ab[6], v[7] + ab[7]);
            sOut[half][cc * 33 + k] = val;   // bank (cc+k)%32: 2-way, free
#pragma unroll
            for (int i = 7; i > 0; --i) ab[i] = ab[i - 1];
            ab[0] = val;
        }
    }
    __syncthreads();

    // alpha[n] (n>=1) at sOut[0][((n-1)>>5)*33 + ((n-1)&31)]; alpha[0]=0.
    // beta[x]  (x< T) at sOut[1][(s>>5)*33 + (s&31)], s = T-1-x; beta[T]=0.

    // ---- scatter: 16K atomicAdds (out already zero-filled by kernel 1) ----
    const float aT = sOut[0][((T - 1) >> 5) * 33 + ((T - 1) & 31)];
    for (int o = tid; o < T * L; o += 1024) {
        int m = midx[o];
        if (m < 0) continue;
        int t = o >> 3, j = o & 7;
        int nx = t + j + 1;
        if (nx > T) nx = T;
        float a = (t == 0) ? 0.f : sOut[0][((t - 1) >> 5) * 33 + ((t - 1) & 31)];
        float b = 0.f;
        if (nx < T) {
            int s = T - 1 - nx;
            b = sOut[1][(s >> 5) * 33 + (s & 31)];
        }
        float w2 = sW[swa(t, j)];   // = logp[m] * LOG2E (staged)
        atomicAdd(&out[(size_t)t * V + m], hexp2(a + w2 + b - aT));
    }
}

extern "C" void kernel_launch(void* const* d_in, const int* in_sizes, int n_in,
                              void* d_out, int out_size, void* d_ws, size_t ws_size,
                              hipStream_t stream) {
    const float* logp = (const float*)d_in[0];   // [V]
    const int*   midx = (const int*)d_in[1];     // [T, L]
    float* out = (float*)d_out;                  // [T, V]

    fill_kernel<<<dim3(T), 256, 0, stream>>>(out);
    scan_scatter_kernel<<<dim3(1), 1024, 0, stream>>>(logp, midx, out);
}

// Round 4
// 294.941 us; speedup vs baseline: 1.0589x; 1.0589x over previous
//
#include <hip/hip_runtime.h>

// UnigramLM forward-backward posterior, T=2048, L=8, V=32000.
// R11: A/B the fill path — let the runtime zero the output.
//   1. scan_kernel   (R9-proven): 2 blocks x 512 — block 0 fwd scan, block 1
//      bwd scan, alpha/beta (log2 domain) -> workspace.             ~12 us
//   2. hipMemsetAsync(out, 0): dispatches __amd_rocclr_fillBufferAligned,
//      the SAME kernel the harness poison uses at 6.6 TB/s.         ~45 us
//   3. scatter_kernel (R7-proven): 64 blocks x 256, one atomicAdd per (t,j).
//                                                                   ~5 us
//   Hand-rolled fills plateaued at 2.3 TB/s in three structures; this round
//   decides whether that was our stores or the environment.

#define NEGV -1e9f
#define LOG2E 1.4426950408889634f
constexpr int T = 2048;
constexpr int L = 8;
constexpr int V = 32000;
constexpr int NCH = 64;   // chunks per scan
constexpr int K = 32;     // steps per chunk (NCH*K == T)
constexpr int BLK = 512;
constexpr int CPAD = K * 8 + 4;    // 260 floats/chunk (phase-1/3 pad)

__device__ __forceinline__ float hexp2(float x) { return __builtin_amdgcn_exp2f(x); }
__device__ __forceinline__ float hlog2(float x) { return __builtin_amdgcn_logf(x); }

__device__ __forceinline__ float lse8v(float t0, float t1, float t2, float t3,
                                       float t4, float t5, float t6, float t7) {
    float m = fmaxf(fmaxf(fmaxf(t0, t1), fmaxf(t2, t3)),
                    fmaxf(fmaxf(t4, t5), fmaxf(t6, t7)));
    float s = hexp2(t0 - m) + hexp2(t1 - m) + hexp2(t2 - m) + hexp2(t3 - m)
            + hexp2(t4 - m) + hexp2(t5 - m) + hexp2(t6 - m) + hexp2(t7 - m);
    return m + hlog2(s);
}

__global__ __launch_bounds__(BLK) void scan_kernel(
        const float* __restrict__ logp, const int* __restrict__ midx,
        float* __restrict__ alpha, float* __restrict__ beta) {
    const int tid = threadIdx.x;
    const int bx = blockIdx.x;

    __shared__ __align__(16) float sW[NCH * CPAD];   // 66,560 B staged w (log2 dom)
    __shared__ __align__(16) float sPm[NCH * 64];    // 16,384 B chunk operators
    __shared__ float sVst[(NCH + 1) * 8];            //  2,080 B boundary states
    __shared__ float sOut[NCH * 33];                 //  8,448 B padded emit buffer

    // ---- staging: gathers into LDS; row r at sW[(r>>5)*CPAD + (r&31)*8 + j]
    if (bx == 0) {
        // forward: row r holds wrev[r][j] = w[r-j][j]
        for (int o = tid; o < T * L; o += BLK) {
            int r = o >> 3, j = o & 7, t = r - j;
            float v = NEGV;
            if (t >= 0) { int m = midx[(t << 3) + j]; if (m >= 0) v = logp[m] * LOG2E; }
            sW[(r >> 5) * CPAD + (r & 31) * 8 + j] = v;
        }
    } else {
        // backward: row s holds w[T-1-s][j]
        for (int o = tid; o < T * L; o += BLK) {
            int s = o >> 3, j = o & 7, t = T - 1 - s;
            int m = midx[(t << 3) + j];
            sW[(s >> 5) * CPAD + (s & 31) * 8 + j] = (m >= 0) ? logp[m] * LOG2E : NEGV;
        }
    }
    __syncthreads();

    // ---- phase 1: operator composition; thread (c, col); 8 thr/chunk
    {
        const int c = tid >> 3, col = tid & 7;
        float q[8];
#pragma unroll
        for (int i = 0; i < 8; ++i) q[i] = (i == col) ? 0.f : NEGV;
        const float* wc = &sW[c * CPAD];
        float4 c0 = *(const float4*)(wc + 0), c1 = *(const float4*)(wc + 4);
        float4 b0 = *(const float4*)(wc + 8), b1 = *(const float4*)(wc + 12);
        for (int k = 0; k < K; ++k) {
            float4 a0, a1;
            if (k + 2 < K) {
                a0 = *(const float4*)(wc + (k + 2) * 8);
                a1 = *(const float4*)(wc + (k + 2) * 8 + 4);
            }
            float top = lse8v(c0.x + q[0], c0.y + q[1], c0.z + q[2], c0.w + q[3],
                              c1.x + q[4], c1.y + q[5], c1.z + q[6], c1.w + q[7]);
#pragma unroll
            for (int i = 7; i > 0; --i) q[i] = q[i - 1];
            q[0] = top;
            c0 = b0; c1 = b1; b0 = a0; b1 = a1;
        }
#pragma unroll
        for (int i = 0; i < 8; ++i) sPm[c * 64 + i * 8 + col] = q[i];
    }
    __syncthreads();

    // ---- phase 2: sequential combine across chunks (lanes 0..7, LDS prefetch)
    if (tid < 8) {
        const int r = tid;
        float v = (r == 0) ? 0.f : NEGV;
        float4 r0 = *(const float4*)&sPm[r * 8];
        float4 r1 = *(const float4*)&sPm[r * 8 + 4];
        for (int cc = 0; cc < NCH; ++cc) {
            sVst[cc * 8 + r] = v;
            float4 n0, n1;
            if (cc + 1 < NCH) {
                n0 = *(const float4*)&sPm[(cc + 1) * 64 + r * 8];
                n1 = *(const float4*)&sPm[(cc + 1) * 64 + r * 8 + 4];
            }
            float vb0 = __shfl(v, 0, 8), vb1 = __shfl(v, 1, 8);
            float vb2 = __shfl(v, 2, 8), vb3 = __shfl(v, 3, 8);
            float vb4 = __shfl(v, 4, 8), vb5 = __shfl(v, 5, 8);
            float vb6 = __shfl(v, 6, 8), vb7 = __shfl(v, 7, 8);
            v = lse8v(r0.x + vb0, r0.y + vb1, r0.z + vb2, r0.w + vb3,
                      r1.x + vb4, r1.y + vb5, r1.z + vb6, r1.w + vb7);
            r0 = n0; r1 = n1;
        }
        sVst[NCH * 8 + r] = v;
    }
    __syncthreads();

    // ---- phase 3: re-run each chunk from boundary state into padded emit buf
    if (tid < NCH) {
        const int cc = tid;
        float ab[8];
#pragma unroll
        for (int i = 0; i < 8; ++i) ab[i] = sVst[cc * 8 + i];
        const float* wc = &sW[cc * CPAD];
        float4 c0 = *(const float4*)(wc + 0), c1 = *(const float4*)(wc + 4);
        float4 b0 = *(const float4*)(wc + 8), b1 = *(const float4*)(wc + 12);
        for (int k = 0; k < K; ++k) {
            float4 a0, a1;
            if (k + 2 < K) {
                a0 = *(const float4*)(wc + (k + 2) * 8);
                a1 = *(const float4*)(wc + (k + 2) * 8 + 4);
            }
            float val = lse8v(c0.x + ab[0], c0.y + ab[1], c0.z + ab[2], c0.w + ab[3],
                              c1.x + ab[4], c1.y + ab[5], c1.z + ab[6], c1.w + ab[7]);
            sOut[cc * 33 + k] = val;   // bank (cc+k)%32: 2-way, free
#pragma unroll
            for (int i = 7; i > 0; --i) ab[i] = ab[i - 1];
            ab[0] = val;
            c0 = b0; c1 = b1; b0 = a0; b1 = a1;
        }
    }
    __syncthreads();

    // ---- coalesced dump of alpha / beta to global (log2 domain)
    if (bx == 0) {
        for (int o = tid; o < T; o += BLK)
            alpha[o + 1] = sOut[(o >> 5) * 33 + (o & 31)];
        if (tid == 0) alpha[0] = 0.f;
    } else {
        for (int o = tid; o < T; o += BLK) {
            int s = T - 1 - o;   // phase3 step s emitted beta[T-1-s]
            beta[o] = sOut[(s >> 5) * 33 + (s & 31)];
        }
        if (tid == 0) beta[T] = 0.f;
    }
}

__global__ __launch_bounds__(256) void scatter_kernel(
        const float* __restrict__ logp, const int* __restrict__ midx,
        float* __restrict__ out, const float* __restrict__ alpha,
        const float* __restrict__ beta) {
    int i = blockIdx.x * blockDim.x + threadIdx.x;
    if (i >= T * L) return;
    int m = midx[i];
    if (m < 0) return;
    int t = i >> 3, j = i & 7;
    int nx = t + j + 1;
    if (nx > T) nx = T;
    float lp2 = alpha[t] + logp[m] * LOG2E + beta[nx] - alpha[T];
    atomicAdd(&out[(size_t)t * V + m], hexp2(lp2));
}

extern "C" void kernel_launch(void* const* d_in, const int* in_sizes, int n_in,
                              void* d_out, int out_size, void* d_ws, size_t ws_size,
                              hipStream_t stream) {
    const float* logp = (const float*)d_in[0];   // [V]
    const int*   midx = (const int*)d_in[1];     // [T, L]
    float* out = (float*)d_out;                  // [T, V]

    float* ws    = (float*)d_ws;
    float* alpha = ws;                 // 2049 -> pad 2064 (log2 domain)
    float* beta  = alpha + 2064;       // 2049 (log2 domain)

    // 1. scans (don't touch out)
    scan_kernel<<<dim3(2), BLK, 0, stream>>>(logp, midx, alpha, beta);
    // 2. zero the output via the runtime's fill kernel (6.6 TB/s measured)
    hipMemsetAsync(d_out, 0, (size_t)T * V * sizeof(float), stream);
    // 3. 16K atomic scatter onto the zeroed output
    scatter_kernel<<<dim3((T * L) / 256), 256, 0, stream>>>(logp, midx, out, alpha, beta);
}

// Round 6
// 294.734 us; speedup vs baseline: 1.0597x; 1.0007x over previous
//
#include <hip/hip_runtime.h>

// UnigramLM forward-backward posterior, T=2048, L=8, V=32000.
// R12b: exact R7 structure (best measured: 288 us) with ONE variable changed —
//      fill stores are nontemporal (global_store_dwordx4 nt, evict-first).
//      (R12 compile fix: __builtin_nontemporal_store needs a clang native
//       vector type, not HIP's float4 class.)
//   Kernel A: block 0 = forward scan, block 1 = backward scan,
//             blocks 2.. = 262MB zero-fill (concurrent with scans).
//   Kernel B: scatter exp2(alpha2[t] + w2 + beta2[t+l] - alpha2[T]) via atomicAdd.
// A/B question: is the in-context fill ceiling (~3 TB/s vs the poison's
// 6.6 TB/s with the SAME-shaped rocclr kernel) cache-policy (nt fixes it)
// or environmental (post-poison DVFS; nothing fixes it).

#define NEGV -1e9f
#define LOG2E 1.4426950408889634f
constexpr int T = 2048;
constexpr int L = 8;
constexpr int V = 32000;
constexpr int NCH = 64;   // chunks per scan
constexpr int K = 32;     // steps per chunk (NCH*K == T)
constexpr int BLK = 512;
constexpr int FILLB = 4096;            // fill blocks; 64,000 B each
constexpr int N4 = T * V / 4;          // 16,384,000 float4s
constexpr int CH4 = N4 / FILLB;        // 4000 per fill block (exact)
constexpr int CPAD = K * 8 + 4;        // 260 floats/chunk: +16B pad → phase-3
                                       // lane stride 1040B = 65x16 → 8 bank-starts

typedef float floatx4 __attribute__((ext_vector_type(4)));   // native vec for nt store

__device__ __forceinline__ float hexp2(float x) { return __builtin_amdgcn_exp2f(x); }
__device__ __forceinline__ float hlog2(float x) { return __builtin_amdgcn_logf(x); }

__device__ __forceinline__ float lse8v(float t0, float t1, float t2, float t3,
                                       float t4, float t5, float t6, float t7) {
    float m = fmaxf(fmaxf(fmaxf(t0, t1), fmaxf(t2, t3)),
                    fmaxf(fmaxf(t4, t5), fmaxf(t6, t7)));
    float s = hexp2(t0 - m) + hexp2(t1 - m) + hexp2(t2 - m) + hexp2(t3 - m)
            + hexp2(t4 - m) + hexp2(t5 - m) + hexp2(t6 - m) + hexp2(t7 - m);
    return m + hlog2(s);
}

__global__ __launch_bounds__(BLK) void scan_fill_kernel(
        const float* __restrict__ logp, const int* __restrict__ midx,
        float* __restrict__ out, float* __restrict__ alpha, float* __restrict__ beta) {
    const int tid = threadIdx.x;
    const int bx = blockIdx.x;

    if (bx >= 2) {
        // ---- contiguous zero-fill, NONTEMPORAL 16B stores (evict-first) ----
        floatx4 z = (floatx4)(0.f);
        floatx4* o4 = (floatx4*)out;
        const int base4 = (bx - 2) * CH4;
        const int end4 = base4 + CH4;
        for (int i = base4 + tid; i < end4; i += BLK)
            __builtin_nontemporal_store(z, o4 + i);
        return;
    }

    __shared__ __align__(16) float sW[NCH * CPAD];   // 66,560 B staged w (log2 dom)
    __shared__ __align__(16) float sPm[NCH * 64];    // 16,384 B chunk operators
    __shared__ float sVst[(NCH + 1) * 8];            // boundary states
    __shared__ float sOut[NCH * 33];                 // 8,448 B padded emit buffer

    // ---- staging: gathers into LDS; row r lives at sW[(r>>5)*CPAD + (r&31)*8 + j]
    if (bx == 0) {
        // forward: row r holds wrev[r][j] = w[r-j][j]
        for (int o = tid; o < T * L; o += BLK) {
            int r = o >> 3, j = o & 7, t = r - j;
            float v = NEGV;
            if (t >= 0) { int m = midx[(t << 3) + j]; if (m >= 0) v = logp[m] * LOG2E; }
            sW[(r >> 5) * CPAD + (r & 31) * 8 + j] = v;
        }
    } else {
        // backward: row s holds w[T-1-s][j]
        for (int o = tid; o < T * L; o += BLK) {
            int s = o >> 3, j = o & 7, t = T - 1 - s;
            int m = midx[(t << 3) + j];
            sW[(s >> 5) * CPAD + (s & 31) * 8 + j] = (m >= 0) ? logp[m] * LOG2E : NEGV;
        }
    }
    __syncthreads();

    // ---- phase 1: operator composition; thread (c, col); 8 thr/chunk broadcast reads
    {
        const int c = tid >> 3, col = tid & 7;
        float q[8];
#pragma unroll
        for (int i = 0; i < 8; ++i) q[i] = (i == col) ? 0.f : NEGV;
        const float* wc = &sW[c * CPAD];
        float4 c0 = *(const float4*)(wc + 0), c1 = *(const float4*)(wc + 4);
        float4 b0 = *(const float4*)(wc + 8), b1 = *(const float4*)(wc + 12);
        for (int k = 0; k < K; ++k) {
            float4 a0, a1;
            if (k + 2 < K) {
                a0 = *(const float4*)(wc + (k + 2) * 8);
                a1 = *(const float4*)(wc + (k + 2) * 8 + 4);
            }
            float top = lse8v(c0.x + q[0], c0.y + q[1], c0.z + q[2], c0.w + q[3],
                              c1.x + q[4], c1.y + q[5], c1.z + q[6], c1.w + q[7]);
#pragma unroll
            for (int i = 7; i > 0; --i) q[i] = q[i - 1];
            q[0] = top;
            c0 = b0; c1 = b1; b0 = a0; b1 = a1;
        }
#pragma unroll
        for (int i = 0; i < 8; ++i) sPm[c * 64 + i * 8 + col] = q[i];
    }
    __syncthreads();

    // ---- phase 2: sequential combine across chunks (lanes 0..7, LDS prefetch)
    if (tid < 8) {
        const int r = tid;
        float v = (r == 0) ? 0.f : NEGV;
        float4 r0 = *(const float4*)&sPm[r * 8];
        float4 r1 = *(const float4*)&sPm[r * 8 + 4];
        for (int cc = 0; cc < NCH; ++cc) {
            sVst[cc * 8 + r] = v;
            float4 n0, n1;
            if (cc + 1 < NCH) {
                n0 = *(const float4*)&sPm[(cc + 1) * 64 + r * 8];
                n1 = *(const float4*)&sPm[(cc + 1) * 64 + r * 8 + 4];
            }
            float vb0 = __shfl(v, 0, 8), vb1 = __shfl(v, 1, 8);
            float vb2 = __shfl(v, 2, 8), vb3 = __shfl(v, 3, 8);
            float vb4 = __shfl(v, 4, 8), vb5 = __shfl(v, 5, 8);
            float vb6 = __shfl(v, 6, 8), vb7 = __shfl(v, 7, 8);
            v = lse8v(r0.x + vb0, r0.y + vb1, r0.z + vb2, r0.w + vb3,
                      r1.x + vb4, r1.y + vb5, r1.z + vb6, r1.w + vb7);
            r0 = n0; r1 = n1;
        }
        sVst[NCH * 8 + r] = v;
    }
    __syncthreads();

    // ---- phase 3: re-run each chunk from boundary state, emit into padded sOut
    if (tid < NCH) {
        const int cc = tid;
        float ab[8];
#pragma unroll
        for (int i = 0; i < 8; ++i) ab[i] = sVst[cc * 8 + i];
        const float* wc = &sW[cc * CPAD];
        float4 c0 = *(const float4*)(wc + 0), c1 = *(const float4*)(wc + 4);
        float4 b0 = *(const float4*)(wc + 8), b1 = *(const float4*)(wc + 12);
        for (int k = 0; k < K; ++k) {
            float4 a0, a1;
            if (k + 2 < K) {
                a0 = *(const float4*)(wc + (k + 2) * 8);
                a1 = *(const float4*)(wc + (k + 2) * 8 + 4);
            }
            float val = lse8v(c0.x + ab[0], c0.y + ab[1], c0.z + ab[2], c0.w + ab[3],
                              c1.x + ab[4], c1.y + ab[5], c1.z + ab[6], c1.w + ab[7]);
            sOut[cc * 33 + k] = val;   // bank (cc+k)%32: 2-way, free
#pragma unroll
            for (int i = 7; i > 0; --i) ab[i] = ab[i - 1];
            ab[0] = val;
            c0 = b0; c1 = b1; b0 = a0; b1 = a1;
        }
    }
    __syncthreads();

    // ---- coalesced dump of alpha / beta to global
    if (bx == 0) {
        for (int o = tid; o < T; o += BLK)
            alpha[o + 1] = sOut[(o >> 5) * 33 + (o & 31)];
        if (tid == 0) alpha[0] = 0.f;
    } else {
        for (int o = tid; o < T; o += BLK) {
            int s = T - 1 - o;   // phase3 step s emitted beta[T-1-s]
            beta[o] = sOut[(s >> 5) * 33 + (s & 31)];
        }
        if (tid == 0) beta[T] = 0.f;
    }
}

__global__ __launch_bounds__(256) void scatter_kernel(
        const float* __restrict__ logp, const int* __restrict__ midx,
        float* __restrict__ out, const float* __restrict__ alpha,
        const float* __restrict__ beta) {
    int i = blockIdx.x * blockDim.x + threadIdx.x;
    if (i >= T * L) return;
    int m = midx[i];
    if (m < 0) return;
    int t = i >> 3, j = i & 7;
    int nx = t + j + 1;
    if (nx > T) nx = T;
    float lp2 = alpha[t] + logp[m] * LOG2E + beta[nx] - alpha[T];
    atomicAdd(&out[(size_t)t * V + m], hexp2(lp2));
}

extern "C" void kernel_launch(void* const* d_in, const int* in_sizes, int n_in,
                              void* d_out, int out_size, void* d_ws, size_t ws_size,
                              hipStream_t stream) {
    const float* logp = (const float*)d_in[0];   // [V]
    const int*   midx = (const int*)d_in[1];     // [T, L]
    float* out = (float*)d_out;                  // [T, V]

    float* ws    = (float*)d_ws;
    float* alpha = ws;                 // 2049 -> pad 2064 (log2 domain)
    float* beta  = alpha + 2064;       // 2049 (log2 domain)

    scan_fill_kernel<<<dim3(2 + FILLB), BLK, 0, stream>>>(logp, midx, out, alpha, beta);
    scatter_kernel<<<dim3((T * L) / 256), 256, 0, stream>>>(logp, midx, out, alpha, beta);
}

// Round 7
// 285.997 us; speedup vs baseline: 1.0920x; 1.0305x over previous
//
#include <hip/hip_runtime.h>

// UnigramLM forward-backward posterior, T=2048, L=8, V=32000.
// R13 = exact R7 (best harness-verified: 286-288 us). Final state.
//   Kernel A: block 0 = forward scan, block 1 = backward scan,
//             blocks 2.. = 262MB zero-fill (concurrent with scans).
//   Kernel B: scatter exp2(alpha2[t] + w2 + beta2[t+l] - alpha2[T]).
// Session conclusion: the 262 MB output write is mandatory and runs at the
// slot-limited ~3 TB/s (even the vendor's own rocclr fill / hipMemsetAsync
// runs ~3 TB/s in our slot vs 6.6 TB/s in the poison slot — environmental,
// best-fit: DVFS ramp after the harness reset()'s tiny-dispatch idle gap).
// All structural alternatives (fused single-kernel, split scan/fill/scatter,
// memset node, nontemporal stores) measured 294-365 us vs R7's 288.

#define NEGV -1e9f
#define LOG2E 1.4426950408889634f
constexpr int T = 2048;
constexpr int L = 8;
constexpr int V = 32000;
constexpr int NCH = 64;   // chunks per scan
constexpr int K = 32;     // steps per chunk (NCH*K == T)
constexpr int BLK = 512;
constexpr int FILLB = 4096;            // fill blocks; 64,000 B each
constexpr int N4 = T * V / 4;          // 16,384,000 float4s
constexpr int CH4 = N4 / FILLB;        // 4000 per fill block (exact)
constexpr int CPAD = K * 8 + 4;        // 260 floats/chunk: +16B pad → phase-3
                                       // lane stride 1040B = 65x16 → 8 bank-starts

__device__ __forceinline__ float hexp2(float x) { return __builtin_amdgcn_exp2f(x); }
__device__ __forceinline__ float hlog2(float x) { return __builtin_amdgcn_logf(x); }

__device__ __forceinline__ float lse8v(float t0, float t1, float t2, float t3,
                                       float t4, float t5, float t6, float t7) {
    float m = fmaxf(fmaxf(fmaxf(t0, t1), fmaxf(t2, t3)),
                    fmaxf(fmaxf(t4, t5), fmaxf(t6, t7)));
    float s = hexp2(t0 - m) + hexp2(t1 - m) + hexp2(t2 - m) + hexp2(t3 - m)
            + hexp2(t4 - m) + hexp2(t5 - m) + hexp2(t6 - m) + hexp2(t7 - m);
    return m + hlog2(s);
}

__global__ __launch_bounds__(BLK) void scan_fill_kernel(
        const float* __restrict__ logp, const int* __restrict__ midx,
        float* __restrict__ out, float* __restrict__ alpha, float* __restrict__ beta) {
    const int tid = threadIdx.x;
    const int bx = blockIdx.x;

    if (bx >= 2) {
        // ---- contiguous zero-fill, plain 16B stores (rocclr-style) ----
        float4 z = make_float4(0.f, 0.f, 0.f, 0.f);
        float4* o4 = (float4*)out;
        const int base4 = (bx - 2) * CH4;
        const int end4 = base4 + CH4;
        for (int i = base4 + tid; i < end4; i += BLK) o4[i] = z;
        return;
    }

    __shared__ __align__(16) float sW[NCH * CPAD];   // 66,560 B staged w (log2 dom)
    __shared__ __align__(16) float sPm[NCH * 64];    // 16,384 B chunk operators
    __shared__ float sVst[(NCH + 1) * 8];            // boundary states
    __shared__ float sOut[NCH * 33];                 // 8,448 B padded emit buffer

    // ---- staging: gathers into LDS; row r lives at sW[(r>>5)*CPAD + (r&31)*8 + j]
    if (bx == 0) {
        // forward: row r holds wrev[r][j] = w[r-j][j]
        for (int o = tid; o < T * L; o += BLK) {
            int r = o >> 3, j = o & 7, t = r - j;
            float v = NEGV;
            if (t >= 0) { int m = midx[(t << 3) + j]; if (m >= 0) v = logp[m] * LOG2E; }
            sW[(r >> 5) * CPAD + (r & 31) * 8 + j] = v;
        }
    } else {
        // backward: row s holds w[T-1-s][j]
        for (int o = tid; o < T * L; o += BLK) {
            int s = o >> 3, j = o & 7, t = T - 1 - s;
            int m = midx[(t << 3) + j];
            sW[(s >> 5) * CPAD + (s & 31) * 8 + j] = (m >= 0) ? logp[m] * LOG2E : NEGV;
        }
    }
    __syncthreads();

    // ---- phase 1: operator composition; thread (c, col); 8 thr/chunk broadcast reads
    {
        const int c = tid >> 3, col = tid & 7;
        float q[8];
#pragma unroll
        for (int i = 0; i < 8; ++i) q[i] = (i == col) ? 0.f : NEGV;
        const float* wc = &sW[c * CPAD];
        float4 c0 = *(const float4*)(wc + 0), c1 = *(const float4*)(wc + 4);
        float4 b0 = *(const float4*)(wc + 8), b1 = *(const float4*)(wc + 12);
        for (int k = 0; k < K; ++k) {
            float4 a0, a1;
            if (k + 2 < K) {
                a0 = *(const float4*)(wc + (k + 2) * 8);
                a1 = *(const float4*)(wc + (k + 2) * 8 + 4);
            }
            float top = lse8v(c0.x + q[0], c0.y + q[1], c0.z + q[2], c0.w + q[3],
                              c1.x + q[4], c1.y + q[5], c1.z + q[6], c1.w + q[7]);
#pragma unroll
            for (int i = 7; i > 0; --i) q[i] = q[i - 1];
            q[0] = top;
            c0 = b0; c1 = b1; b0 = a0; b1 = a1;
        }
#pragma unroll
        for (int i = 0; i < 8; ++i) sPm[c * 64 + i * 8 + col] = q[i];
    }
    __syncthreads();

    // ---- phase 2: sequential combine across chunks (lanes 0..7, LDS prefetch)
    if (tid < 8) {
        const int r = tid;
        float v = (r == 0) ? 0.f : NEGV;
        float4 r0 = *(const float4*)&sPm[r * 8];
        float4 r1 = *(const float4*)&sPm[r * 8 + 4];
        for (int cc = 0; cc < NCH; ++cc) {
            sVst[cc * 8 + r] = v;
            float4 n0, n1;
            if (cc + 1 < NCH) {
                n0 = *(const float4*)&sPm[(cc + 1) * 64 + r * 8];
                n1 = *(const float4*)&sPm[(cc + 1) * 64 + r * 8 + 4];
            }
            float vb0 = __shfl(v, 0, 8), vb1 = __shfl(v, 1, 8);
            float vb2 = __shfl(v, 2, 8), vb3 = __shfl(v, 3, 8);
            float vb4 = __shfl(v, 4, 8), vb5 = __shfl(v, 5, 8);
            float vb6 = __shfl(v, 6, 8), vb7 = __shfl(v, 7, 8);
            v = lse8v(r0.x + vb0, r0.y + vb1, r0.z + vb2, r0.w + vb3,
                      r1.x + vb4, r1.y + vb5, r1.z + vb6, r1.w + vb7);
            r0 = n0; r1 = n1;
        }
        sVst[NCH * 8 + r] = v;
    }
    __syncthreads();

    // ---- phase 3: re-run each chunk from boundary state, emit into padded sOut
    if (tid < NCH) {
        const int cc = tid;
        float ab[8];
#pragma unroll
        for (int i = 0; i < 8; ++i) ab[i] = sVst[cc * 8 + i];
        const float* wc = &sW[cc * CPAD];
        float4 c0 = *(const float4*)(wc + 0), c1 = *(const float4*)(wc + 4);
        float4 b0 = *(const float4*)(wc + 8), b1 = *(const float4*)(wc + 12);
        for (int k = 0; k < K; ++k) {
            float4 a0, a1;
            if (k + 2 < K) {
                a0 = *(const float4*)(wc + (k + 2) * 8);
                a1 = *(const float4*)(wc + (k + 2) * 8 + 4);
            }
            float val = lse8v(c0.x + ab[0], c0.y + ab[1], c0.z + ab[2], c0.w + ab[3],
                              c1.x + ab[4], c1.y + ab[5], c1.z + ab[6], c1.w + ab[7]);
            sOut[cc * 33 + k] = val;   // bank (cc+k)%32: 2-way, free
#pragma unroll
            for (int i = 7; i > 0; --i) ab[i] = ab[i - 1];
            ab[0] = val;
            c0 = b0; c1 = b1; b0 = a0; b1 = a1;
        }
    }
    __syncthreads();

    // ---- coalesced dump of alpha / beta to global
    if (bx == 0) {
        for (int o = tid; o < T; o += BLK)
            alpha[o + 1] = sOut[(o >> 5) * 33 + (o & 31)];
        if (tid == 0) alpha[0] = 0.f;
    } else {
        for (int o = tid; o < T; o += BLK) {
            int s = T - 1 - o;   // phase3 step s emitted beta[T-1-s]
            beta[o] = sOut[(s >> 5) * 33 + (s & 31)];
        }
        if (tid == 0) beta[T] = 0.f;
    }
}

__global__ __launch_bounds__(256) void scatter_kernel(
        const float* __restrict__ logp, const int* __restrict__ midx,
        float* __restrict__ out, const float* __restrict__ alpha,
        const float* __restrict__ beta) {
    int i = blockIdx.x * blockDim.x + threadIdx.x;
    if (i >= T * L) return;
    int m = midx[i];
    if (m < 0) return;
    int t = i >> 3, j = i & 7;
    int nx = t + j + 1;
    if (nx > T) nx = T;
    float lp2 = alpha[t] + logp[m] * LOG2E + beta[nx] - alpha[T];
    atomicAdd(&out[(size_t)t * V + m], hexp2(lp2));
}

extern "C" void kernel_launch(void* const* d_in, const int* in_sizes, int n_in,
                              void* d_out, int out_size, void* d_ws, size_t ws_size,
                              hipStream_t stream) {
    const float* logp = (const float*)d_in[0];   // [V]
    const int*   midx = (const int*)d_in[1];     // [T, L]
    float* out = (float*)d_out;                  // [T, V]

    float* ws    = (float*)d_ws;
    float* alpha = ws;                 // 2049 -> pad 2064 (log2 domain)
    float* beta  = alpha + 2064;       // 2049 (log2 domain)

    scan_fill_kernel<<<dim3(2 + FILLB), BLK, 0, stream>>>(logp, midx, out, alpha, beta);
    scatter_kernel<<<dim3((T * L) / 256), 256, 0, stream>>>(logp, midx, out, alpha, beta);
}